// Round 3
// baseline (132.314 us; speedup 1.0000x reference)
//
#include <hip/hip_runtime.h>
#include <hip/hip_cooperative_groups.h>

namespace cg = cooperative_groups;

#define NN 1024
#define EMBED 256
#define HID 128
#define EPS 1e-8f
#define INV_N (1.0f / 1024.0f)
#define LDSPITCH 132  // 128 + 4: breaks power-of-2 LDS row stride, keeps 16B alignment

// ---------------------------------------------------------------------------
// Single cooperative kernel: 256 blocks x 256 threads, 1 block/CU.
// Phase A: hs' = src @ W1[:256] + b1 ; ht = tgt @ W1[256:]   (4+4 rows/block)
// Phase B: C[i,j] = relu(hs'[i]+ht[j]) . W2 + b2, + rowsum of exp(-C)
// Phase C: t[j] = sum_i exp(-C[i,j]) * u[i]
// Phase D: plan = u .* exp(-C) .* v
// Fused into one dispatch: the 4-dispatch version paid ~5 us fixed cost per
// graph node (39.4 us total vs ~15 us of work).
// ---------------------------------------------------------------------------
__global__ __launch_bounds__(256) void fusedNOT(const float* __restrict__ src,
                                                const float* __restrict__ tgt,
                                                const float* __restrict__ W1,
                                                const float* __restrict__ b1,
                                                const float* __restrict__ W2,
                                                const float* __restrict__ b2,
                                                float* __restrict__ plan,
                                                float* __restrict__ Cmat,
                                                float* __restrict__ hsp,
                                                float* __restrict__ htp,
                                                float* __restrict__ rowsum,
                                                float* __restrict__ tcol) {
    __shared__ float hsL[64 * LDSPITCH];  // 33 KB (phase A reuses first 8 KB)
    __shared__ float htL[64 * LDSPITCH];  // 33 KB
    __shared__ float w2L[HID];
    __shared__ float rsL[64];

    cg::grid_group grid = cg::this_grid();
    const int b = blockIdx.x;
    const int tid = threadIdx.x;

    // ---------------- Phase A ----------------
    {
        if (b < 8) rowsum[b * 256 + tid] = 0.0f;  // zero rowsum[1024] ++ tcol[1024]

        float* s = hsL;  // [8][256] staging: rows 0-3 src, 4-7 tgt
        const int r0 = b * 4;
        {
            const float4* gs = (const float4*)(src + r0 * EMBED);
            const float4* gt = (const float4*)(tgt + r0 * EMBED);
            float4* sv = (float4*)s;
            sv[tid] = gs[tid];          // 256 float4 = 4 src rows
            sv[tid + 256] = gt[tid];    // 4 tgt rows
        }
        __syncthreads();

        const int h = tid & 127;
        const int rr = tid >> 7;  // 0 or 1; thread owns rows {rr, rr+2}
        const float* __restrict__ ws = W1;                 // src half [256][128]
        const float* __restrict__ wt = W1 + EMBED * HID;   // tgt half
        float as0 = 0.f, as1 = 0.f, at0 = 0.f, at1 = 0.f;

        for (int k = 0; k < EMBED; k += 4) {
            const float ws0 = ws[(k + 0) * HID + h];
            const float ws1 = ws[(k + 1) * HID + h];
            const float ws2 = ws[(k + 2) * HID + h];
            const float ws3 = ws[(k + 3) * HID + h];
            const float wt0 = wt[(k + 0) * HID + h];
            const float wt1 = wt[(k + 1) * HID + h];
            const float wt2 = wt[(k + 2) * HID + h];
            const float wt3 = wt[(k + 3) * HID + h];
            const float4 ss0 = *(const float4*)&s[(rr + 0) * EMBED + k];
            const float4 ss1 = *(const float4*)&s[(rr + 2) * EMBED + k];
            const float4 st0 = *(const float4*)&s[(4 + rr + 0) * EMBED + k];
            const float4 st1 = *(const float4*)&s[(4 + rr + 2) * EMBED + k];
            as0 = fmaf(ss0.x, ws0, as0); as0 = fmaf(ss0.y, ws1, as0);
            as0 = fmaf(ss0.z, ws2, as0); as0 = fmaf(ss0.w, ws3, as0);
            as1 = fmaf(ss1.x, ws0, as1); as1 = fmaf(ss1.y, ws1, as1);
            as1 = fmaf(ss1.z, ws2, as1); as1 = fmaf(ss1.w, ws3, as1);
            at0 = fmaf(st0.x, wt0, at0); at0 = fmaf(st0.y, wt1, at0);
            at0 = fmaf(st0.z, wt2, at0); at0 = fmaf(st0.w, wt3, at0);
            at1 = fmaf(st1.x, wt0, at1); at1 = fmaf(st1.y, wt1, at1);
            at1 = fmaf(st1.z, wt2, at1); at1 = fmaf(st1.w, wt3, at1);
        }

        const float bias = b1[h];
        hsp[(r0 + rr + 0) * HID + h] = as0 + bias;
        hsp[(r0 + rr + 2) * HID + h] = as1 + bias;
        htp[(r0 + rr + 0) * HID + h] = at0;
        htp[(r0 + rr + 2) * HID + h] = at1;
    }

    grid.sync();

    // ---------------- Phase B ----------------
    {
        const int j0 = (b & 15) * 64;
        const int i0 = (b >> 4) * 64;

        for (int idx = tid; idx < 64 * 32; idx += 256) {
            const int i = idx >> 5;
            const int h4 = (idx & 31) << 2;
            *(float4*)&hsL[i * LDSPITCH + h4] = *(const float4*)&hsp[(i0 + i) * HID + h4];
            *(float4*)&htL[i * LDSPITCH + h4] = *(const float4*)&htp[(j0 + i) * HID + h4];
        }
        if (tid < HID) w2L[tid] = W2[tid];
        if (tid < 64) rsL[tid] = 0.0f;
        __syncthreads();

        const int ti = tid & 15;
        const int tj = tid >> 4;
        float acc[4][4] = {};

        for (int h = 0; h < HID; h += 4) {
            const float4 A0 = *(const float4*)&hsL[(ti + 0) * LDSPITCH + h];
            const float4 A1 = *(const float4*)&hsL[(ti + 16) * LDSPITCH + h];
            const float4 A2 = *(const float4*)&hsL[(ti + 32) * LDSPITCH + h];
            const float4 A3 = *(const float4*)&hsL[(ti + 48) * LDSPITCH + h];
            const float4 B0 = *(const float4*)&htL[(tj + 0) * LDSPITCH + h];
            const float4 B1 = *(const float4*)&htL[(tj + 16) * LDSPITCH + h];
            const float4 B2 = *(const float4*)&htL[(tj + 32) * LDSPITCH + h];
            const float4 B3 = *(const float4*)&htL[(tj + 48) * LDSPITCH + h];
            const float4 wv = *(const float4*)&w2L[h];
#define STEP(a, bb, Av, Bv)                                                    \
            {                                                                  \
                float t;                                                       \
                t = Av.x + Bv.x; acc[a][bb] = fmaf(fmaxf(t, 0.f), wv.x, acc[a][bb]); \
                t = Av.y + Bv.y; acc[a][bb] = fmaf(fmaxf(t, 0.f), wv.y, acc[a][bb]); \
                t = Av.z + Bv.z; acc[a][bb] = fmaf(fmaxf(t, 0.f), wv.z, acc[a][bb]); \
                t = Av.w + Bv.w; acc[a][bb] = fmaf(fmaxf(t, 0.f), wv.w, acc[a][bb]); \
            }
            STEP(0, 0, A0, B0) STEP(0, 1, A0, B1) STEP(0, 2, A0, B2) STEP(0, 3, A0, B3)
            STEP(1, 0, A1, B0) STEP(1, 1, A1, B1) STEP(1, 2, A1, B2) STEP(1, 3, A1, B3)
            STEP(2, 0, A2, B0) STEP(2, 1, A2, B1) STEP(2, 2, A2, B2) STEP(2, 3, A2, B3)
            STEP(3, 0, A3, B0) STEP(3, 1, A3, B1) STEP(3, 2, A3, B2) STEP(3, 3, A3, B3)
#undef STEP
        }

        const float b2v = b2[0];
        float rp[4] = {0.f, 0.f, 0.f, 0.f};
        for (int a = 0; a < 4; ++a) {
            const int i = i0 + ti + 16 * a;
            for (int bb = 0; bb < 4; ++bb) {
                const int j = j0 + tj + 16 * bb;
                const float c = acc[a][bb] + b2v;
                Cmat[i * NN + j] = c;
                rp[a] += expf(-c);
            }
        }
        for (int a = 0; a < 4; ++a) atomicAdd(&rsL[ti + 16 * a], rp[a]);
        __syncthreads();
        if (tid < 64) atomicAdd(&rowsum[i0 + tid], rsL[tid]);
    }

    grid.sync();

    // ---------------- Phase C ----------------
    {
        const int jb = b & 3;
        const int ic = b >> 2;
        const int j = jb * 256 + tid;
        float acc = 0.f;
#pragma unroll
        for (int ii = 0; ii < 16; ++ii) {
            const int i = ic * 16 + ii;
            const float u = INV_N / (INV_N * rowsum[i] + EPS);
            const float c = Cmat[i * NN + j];
            acc = fmaf(expf(-c), u, acc);
        }
        atomicAdd(&tcol[j], acc);
    }

    grid.sync();

    // ---------------- Phase D ----------------
    {
        const int i0 = b * 4;
        const int j4 = tid * 4;
        const float4 t4 = *(const float4*)&tcol[j4];
        float4 v4;
        v4.x = INV_N / (t4.x + EPS);
        v4.y = INV_N / (t4.y + EPS);
        v4.z = INV_N / (t4.z + EPS);
        v4.w = INV_N / (t4.w + EPS);
#pragma unroll
        for (int r = 0; r < 4; ++r) {
            const int row = i0 + r;
            const float u = INV_N / (INV_N * rowsum[row] + EPS);
            const float4 c4 = *(const float4*)&Cmat[row * NN + j4];
            float4 p;
            p.x = u * expf(-c4.x) * v4.x;
            p.y = u * expf(-c4.y) * v4.y;
            p.z = u * expf(-c4.z) * v4.z;
            p.w = u * expf(-c4.w) * v4.w;
            *(float4*)&plan[row * NN + j4] = p;
        }
    }
}

// ---------------------------------------------------------------------------
extern "C" void kernel_launch(void* const* d_in, const int* in_sizes, int n_in,
                              void* d_out, int out_size, void* d_ws, size_t ws_size,
                              hipStream_t stream) {
    const float* src = (const float*)d_in[0];   // [1024, 256]
    const float* tgt = (const float*)d_in[1];   // [1024, 256]
    const float* W1  = (const float*)d_in[2];   // [512, 128]
    const float* b1  = (const float*)d_in[3];   // [128]
    const float* W2  = (const float*)d_in[4];   // [128, 1]
    const float* b2  = (const float*)d_in[5];   // [1]

    float* out = (float*)d_out;
    float* plan = out;            // [1024, 1024] (output 0)
    float* Cmat = out + NN * NN;  // [1024, 1024] (output 1)

    float* ws = (float*)d_ws;
    float* hsp    = ws;                 // [1024][128]
    float* htp    = ws + NN * HID;      // [1024][128]
    float* rowsum = ws + 2 * NN * HID;  // [1024]
    float* tcol   = rowsum + NN;        // [1024]

    void* args[] = {(void*)&src, (void*)&tgt, (void*)&W1, (void*)&b1,
                    (void*)&W2, (void*)&b2, (void*)&plan, (void*)&Cmat,
                    (void*)&hsp, (void*)&htp, (void*)&rowsum, (void*)&tcol};
    hipLaunchCooperativeKernel((void*)fusedNOT, dim3(256), dim3(256), args, 0, stream);
}